// Round 5
// baseline (338.486 us; speedup 1.0000x reference)
//
#include <hip/hip_runtime.h>
#include <hip/hip_bf16.h>
#include <math.h>

typedef __bf16 bf16;
typedef __attribute__((ext_vector_type(8))) __bf16 bf16x8;
typedef __attribute__((ext_vector_type(4))) __bf16 bf16x4;
typedef __attribute__((ext_vector_type(4))) float f32x4;

#define EPSBN 1e-5f
#define NSLOT 128

// ---------------- K0: zero stat partials; build bf16 Ahat/W1/W2 in padded layouts ----------------
__global__ __launch_bounds__(256) void k0_prep(const int* __restrict__ edge,
    const float* __restrict__ W1, const float* __restrict__ W2,
    float* __restrict__ partials,          // 32768 floats (part1+part2)
    bf16* __restrict__ ahb,                // [64][72]
    bf16* __restrict__ w1b,                // [64][104]
    bf16* __restrict__ w2b)                // [32][72]
{
    int tid = threadIdx.x;
    for (int i = blockIdx.x * 256 + tid; i < NSLOT * 64 * 4; i += gridDim.x * 256)
        partials[i] = 0.f;
    if (blockIdx.x == 1) {
        for (int i = tid; i < 64 * 104; i += 256) {
            int n = i / 104, f = i % 104;
            w1b[i] = (bf16)((f < 67) ? W1[n * 67 + f] : 0.f);
        }
        return;
    }
    if (blockIdx.x == 2) {
        for (int i = tid; i < 32 * 72; i += 256) {
            int n = i / 72, f = i % 72;
            w2b[i] = (bf16)((f < 64) ? W2[n * 64 + f] : 0.f);
        }
        return;
    }
    if (blockIdx.x != 0) return;

    __shared__ float Ah[64 * 64];
    __shared__ int deg[64];
    __shared__ float dinv[64];
    for (int i = tid; i < 4096; i += 256) Ah[i] = 0.f;
    if (tid < 64) deg[tid] = 1;                       // self loop
    __syncthreads();
    for (int e = tid; e < 512; e += 256) atomicAdd(&deg[edge[512 + e]], 1);
    __syncthreads();
    if (tid < 64) dinv[tid] = rsqrtf((float)deg[tid]);
    __syncthreads();
    for (int e = tid; e < 512; e += 256) {
        int s = edge[e], d = edge[512 + e];
        atomicAdd(&Ah[d * 64 + s], dinv[s] * dinv[d]);
    }
    if (tid < 64) atomicAdd(&Ah[tid * 64 + tid], dinv[tid] * dinv[tid]);
    __syncthreads();
    for (int i = tid; i < 64 * 72; i += 256) {
        int n = i / 72, s = i % 72;
        ahb[i] = (bf16)((s < 64) ? Ah[n * 64 + s] : 0.f);
    }
}

// ---------------- KXC: convert quarter of x (fp32 [64][67]) -> padded bf16 [64][104] ----------------
// grid 512 blocks x 2 samples; chunk = bf16x8; writes fully coalesced.
__global__ __launch_bounds__(256) void kx_conv(const float* __restrict__ x,
    bf16* __restrict__ xbq, int s0)
{
    int tid = threadIdx.x;
    const float* xs = x + ((size_t)s0 + blockIdx.x * 2) * 4288;
    bf16* xo = xbq + (size_t)blockIdx.x * 13312;      // 2 samples * 6656
#pragma unroll
    for (int k = 0; k < 7; ++k) {
        int c = tid + (k << 8);
        if (c < 1664) {
            int ls = c >> 9 >= 1 ? (c >= 832) : (c >= 832);   // ls = c/832
            ls = (c >= 832) ? 1 : 0;
            int cc = c - ls * 832;
            int n = cc / 13;                          // const-div -> magic mul
            int seg = cc - n * 13;
            int f0 = seg * 8;
            const float* src = xs + ls * 4288 + n * 67 + f0;
            bf16x8 v;
#pragma unroll
            for (int j = 0; j < 8; ++j) {
                float t = (f0 + j < 67) ? src[j] : 0.f;
                v[j] = (bf16)t;
            }
            *(bf16x8*)(xo + (size_t)c * 8) = v;
        }
    }
}

// ---------------- K1: GCN layer 1 — 2 samples/block, wave-pair per sample, all-MFMA ----------------
// MFMA1: hT[o][n] = sum_f W1[o][f] X[n][f];  MFMA2: out[n][c] = sum_s Ahat[n][s] hT[c][s]
__global__ __launch_bounds__(256) void k1_gcn1(
    const bf16* __restrict__ xbq,         // [1024][64][104] padded bf16 (quarter)
    const bf16* __restrict__ w1b,         // [64][104]
    const bf16* __restrict__ ahb,         // [64][72]
    const float* __restrict__ b1,
    bf16* __restrict__ g1out,             // [B][64][64]
    float* __restrict__ part1,            // [NSLOT][64][2]
    int s0)
{
    __shared__ bf16 sW[64 * 104];         // 13312 B
    __shared__ bf16 sX[2 * 64 * 104];     // 26624 B; per-sample 6656; overlays hT then out
    __shared__ bf16 sAh[64 * 72];         // 9216 B
    __shared__ float sstat[128];
    int tid = threadIdx.x;
    int blk = blockIdx.x;
    if (tid < 128) sstat[tid] = 0.f;
#pragma unroll
    for (int k = 0; k < 4; ++k) {
        int c = tid + (k << 8);
        if (c < 832) ((bf16x8*)sW)[c] = ((const bf16x8*)w1b)[c];
    }
#pragma unroll
    for (int k = 0; k < 3; ++k) {
        int c = tid + (k << 8);
        if (c < 576) ((bf16x8*)sAh)[c] = ((const bf16x8*)ahb)[c];
    }
    const bf16x8* xp = (const bf16x8*)(xbq + (size_t)blk * 13312);
#pragma unroll
    for (int k = 0; k < 7; ++k) {
        int c = tid + (k << 8);
        if (c < 1664) ((bf16x8*)sX)[c] = xp[c];
    }
    __syncthreads();

    int w = tid >> 6, lane = tid & 63, q = lane >> 4, r15 = lane & 15;
    int sm = w >> 1, hw = w & 1;                      // sample, half (mt-split)
    bf16* myX = sX + sm * 6656;
    f32x4 z4 = {0.f, 0.f, 0.f, 0.f};
    f32x4 acc[2][4];
#pragma unroll
    for (int mt = 0; mt < 2; ++mt)
#pragma unroll
        for (int nt = 0; nt < 4; ++nt) acc[mt][nt] = z4;
#pragma unroll
    for (int kt = 0; kt < 3; ++kt) {
        bf16x8 a_[2], b_[4];
#pragma unroll
        for (int mt = 0; mt < 2; ++mt)
            a_[mt] = *(const bf16x8*)&sW[((hw * 2 + mt) * 16 + r15) * 104 + kt * 32 + q * 8];
#pragma unroll
        for (int nt = 0; nt < 4; ++nt)
            b_[nt] = *(const bf16x8*)&myX[(nt * 16 + r15) * 104 + kt * 32 + q * 8];
#pragma unroll
        for (int mt = 0; mt < 2; ++mt)
#pragma unroll
            for (int nt = 0; nt < 4; ++nt)
                acc[mt][nt] = __builtin_amdgcn_mfma_f32_16x16x32_bf16(a_[mt], b_[nt], acc[mt][nt], 0, 0, 0);
    }
    __syncthreads();                                  // all waves done reading X
    // write hT[o][n], pitch 104 (rows disjoint across wave pair)
#pragma unroll
    for (int mt = 0; mt < 2; ++mt)
#pragma unroll
        for (int nt = 0; nt < 4; ++nt)
#pragma unroll
            for (int r = 0; r < 4; ++r)
                myX[((hw * 2 + mt) * 16 + q * 4 + r) * 104 + nt * 16 + r15] = (bf16)acc[mt][nt][r];

    bf16x8 ah[2][2];
#pragma unroll
    for (int mt = 0; mt < 2; ++mt)
#pragma unroll
        for (int kt = 0; kt < 2; ++kt)
            ah[mt][kt] = *(const bf16x8*)&sAh[((hw * 2 + mt) * 16 + r15) * 72 + kt * 32 + q * 8];
    __syncthreads();                                  // hT complete

    bf16x8 hb[4][2];
#pragma unroll
    for (int ct = 0; ct < 4; ++ct)
#pragma unroll
        for (int kt = 0; kt < 2; ++kt)
            hb[ct][kt] = *(const bf16x8*)&myX[(ct * 16 + r15) * 104 + kt * 32 + q * 8];

    f32x4 o2[2][4];
#pragma unroll
    for (int mt = 0; mt < 2; ++mt)
#pragma unroll
        for (int ct = 0; ct < 4; ++ct) o2[mt][ct] = z4;
#pragma unroll
    for (int kt = 0; kt < 2; ++kt)
#pragma unroll
        for (int mt = 0; mt < 2; ++mt)
#pragma unroll
            for (int ct = 0; ct < 4; ++ct)
                o2[mt][ct] = __builtin_amdgcn_mfma_f32_16x16x32_bf16(ah[mt][kt], hb[ct][kt], o2[mt][ct], 0, 0, 0);

    float bv[4];
#pragma unroll
    for (int ct = 0; ct < 4; ++ct) bv[ct] = b1[ct * 16 + r15];
    __syncthreads();                                  // all hT reads done
    // out staging pitch 72
#pragma unroll
    for (int mt = 0; mt < 2; ++mt)
#pragma unroll
        for (int ct = 0; ct < 4; ++ct)
#pragma unroll
            for (int r = 0; r < 4; ++r)
                myX[((hw * 2 + mt) * 16 + q * 4 + r) * 72 + ct * 16 + r15] = (bf16)(o2[mt][ct][r] + bv[ct]);
    __syncthreads();

    // coalesced store + stats: 1024 16B-chunks (2 samples x 512)
    bf16* gp = g1out + ((size_t)s0 + blk * 2) * 4096;
#pragma unroll
    for (int k = 0; k < 4; ++k) {
        int c = tid + (k << 8);
        int s = c >> 9, rc = c & 511, n = rc >> 3, cc = rc & 7;
        bf16x8 v = *(const bf16x8*)&sX[s * 6656 + n * 72 + cc * 8];
        ((bf16x8*)gp)[c] = v;
        float s1 = 0.f, s2 = 0.f;
#pragma unroll
        for (int j = 0; j < 8; ++j) { float f = (float)v[j]; s1 += f; s2 += f * f; }
        atomicAdd(&sstat[n * 2 + 0], s1);
        atomicAdd(&sstat[n * 2 + 1], s2);
    }
    __syncthreads();
    if (tid < 64) {
        int slot = (s0 + blk * 2) & (NSLOT - 1);
        atomicAdd(&part1[(slot * 64 + tid) * 2 + 0], sstat[tid * 2 + 0]);
        atomicAdd(&part1[(slot * 64 + tid) * 2 + 1], sstat[tid * 2 + 1]);
    }
}

// ---------------- BN stats reduce ----------------
__global__ __launch_bounds__(64) void k_bnstats(
    const float* __restrict__ part,
    const float* __restrict__ gamma, const float* __restrict__ beta,
    float* __restrict__ scale, float* __restrict__ shift, float inv_count)
{
    int n = blockIdx.x, t = threadIdx.x;
    float s1 = part[(t * 64 + n) * 2] + part[((t + 64) * 64 + n) * 2];
    float s2 = part[(t * 64 + n) * 2 + 1] + part[((t + 64) * 64 + n) * 2 + 1];
#pragma unroll
    for (int o = 32; o > 0; o >>= 1) { s1 += __shfl_down(s1, o); s2 += __shfl_down(s2, o); }
    if (t == 0) {
        float mean = s1 * inv_count;
        float var = s2 * inv_count - mean * mean;
        float sc = gamma[n] * rsqrtf(var + EPSBN);
        scale[n] = sc;
        shift[n] = beta[n] - mean * sc;
    }
}

// ---------------- K3: BN1+relu -> GCN layer 2 — 4 samples/block, all-MFMA ----------------
__global__ __launch_bounds__(256) void k3_gcn2(
    const bf16* __restrict__ g1out,
    const bf16* __restrict__ w2b,         // [32][72]
    const bf16* __restrict__ ahb,         // [64][72]
    const float* __restrict__ b2,
    const float* __restrict__ scale1, const float* __restrict__ shift1,
    bf16* __restrict__ g2out,             // [B][64][32]
    float* __restrict__ part2)
{
    __shared__ bf16 sW[32 * 72];
    __shared__ bf16 sY[4 * 64 * 72];
    __shared__ bf16 sAh[64 * 72];
    __shared__ float sstat[128];
    __shared__ float ssc[64], ssh[64];
    int tid = threadIdx.x;
    int blk = blockIdx.x;
    if (tid < 128) sstat[tid] = 0.f;
    if (tid < 64) { ssc[tid] = scale1[tid]; ssh[tid] = shift1[tid]; }
#pragma unroll
    for (int k = 0; k < 2; ++k) {
        int c = tid + (k << 8);
        if (c < 288) ((bf16x8*)sW)[c] = ((const bf16x8*)w2b)[c];
    }
#pragma unroll
    for (int k = 0; k < 3; ++k) {
        int c = tid + (k << 8);
        if (c < 576) ((bf16x8*)sAh)[c] = ((const bf16x8*)ahb)[c];
    }
    __syncthreads();

    const bf16* gb = g1out + (size_t)blk * 16384;
#pragma unroll
    for (int k = 0; k < 8; ++k) {
        int c = tid + (k << 8);
        int s = c >> 9, rc = c & 511, n = rc >> 3, cc = rc & 7;
        bf16x8 g = ((const bf16x8*)gb)[c];
        float sc = ssc[n], sh = ssh[n];
        bf16x8 y;
#pragma unroll
        for (int j = 0; j < 8; ++j)
            y[j] = (bf16)fmaxf(fmaf(sc, (float)g[j], sh), 0.f);
        *(bf16x8*)&sY[s * 4608 + n * 72 + cc * 8] = y;
    }
    __syncthreads();

    int w = tid >> 6, lane = tid & 63, q = lane >> 4, r15 = lane & 15;
    bf16* myY = sY + w * 4608;
    f32x4 z4 = {0.f, 0.f, 0.f, 0.f};
    f32x4 acc[2][4];
#pragma unroll
    for (int mt = 0; mt < 2; ++mt)
#pragma unroll
        for (int nt = 0; nt < 4; ++nt) acc[mt][nt] = z4;
#pragma unroll
    for (int kt = 0; kt < 2; ++kt) {
        bf16x8 a_[2], b_[4];
#pragma unroll
        for (int mt = 0; mt < 2; ++mt)
            a_[mt] = *(const bf16x8*)&sW[(mt * 16 + r15) * 72 + kt * 32 + q * 8];
#pragma unroll
        for (int nt = 0; nt < 4; ++nt)
            b_[nt] = *(const bf16x8*)&myY[(nt * 16 + r15) * 72 + kt * 32 + q * 8];
#pragma unroll
        for (int mt = 0; mt < 2; ++mt)
#pragma unroll
            for (int nt = 0; nt < 4; ++nt)
                acc[mt][nt] = __builtin_amdgcn_mfma_f32_16x16x32_bf16(a_[mt], b_[nt], acc[mt][nt], 0, 0, 0);
    }
#pragma unroll
    for (int mt = 0; mt < 2; ++mt)
#pragma unroll
        for (int nt = 0; nt < 4; ++nt)
#pragma unroll
            for (int r = 0; r < 4; ++r)
                myY[(mt * 16 + q * 4 + r) * 72 + nt * 16 + r15] = (bf16)acc[mt][nt][r];

    bf16x8 ah[4][2], hb[2][2];
#pragma unroll
    for (int mt = 0; mt < 4; ++mt)
#pragma unroll
        for (int kt = 0; kt < 2; ++kt)
            ah[mt][kt] = *(const bf16x8*)&sAh[(mt * 16 + r15) * 72 + kt * 32 + q * 8];
#pragma unroll
    for (int ct = 0; ct < 2; ++ct)
#pragma unroll
        for (int kt = 0; kt < 2; ++kt)
            hb[ct][kt] = *(const bf16x8*)&myY[(ct * 16 + r15) * 72 + kt * 32 + q * 8];

    f32x4 o2[4][2];
#pragma unroll
    for (int mt = 0; mt < 4; ++mt)
#pragma unroll
        for (int ct = 0; ct < 2; ++ct) o2[mt][ct] = z4;
#pragma unroll
    for (int kt = 0; kt < 2; ++kt)
#pragma unroll
        for (int mt = 0; mt < 4; ++mt)
#pragma unroll
            for (int ct = 0; ct < 2; ++ct)
                o2[mt][ct] = __builtin_amdgcn_mfma_f32_16x16x32_bf16(ah[mt][kt], hb[ct][kt], o2[mt][ct], 0, 0, 0);

    float bv[2];
#pragma unroll
    for (int ct = 0; ct < 2; ++ct) bv[ct] = b2[ct * 16 + r15];
#pragma unroll
    for (int mt = 0; mt < 4; ++mt)
#pragma unroll
        for (int ct = 0; ct < 2; ++ct)
#pragma unroll
            for (int r = 0; r < 4; ++r)
                myY[(mt * 16 + q * 4 + r) * 40 + ct * 16 + r15] = (bf16)(o2[mt][ct][r] + bv[ct]);
    __syncthreads();

    bf16* gp = g2out + (size_t)blk * 8192;
#pragma unroll
    for (int k = 0; k < 4; ++k) {
        int c = tid + (k << 8);
        int s = c >> 8, rc = c & 255, n = rc >> 2, cc = rc & 3;
        bf16x8 v = *(const bf16x8*)&sY[s * 4608 + n * 40 + cc * 8];
        ((bf16x8*)gp)[c] = v;
        float s1 = 0.f, s2 = 0.f;
#pragma unroll
        for (int j = 0; j < 8; ++j) { float f = (float)v[j]; s1 += f; s2 += f * f; }
        atomicAdd(&sstat[n * 2 + 0], s1);
        atomicAdd(&sstat[n * 2 + 1], s2);
    }
    __syncthreads();
    if (tid < 64) {
        int slot = blk & (NSLOT - 1);
        atomicAdd(&part2[(slot * 64 + tid) * 2 + 0], sstat[tid * 2 + 0]);
        atomicAdd(&part2[(slot * 64 + tid) * 2 + 1], sstat[tid * 2 + 1]);
    }
}

// ---------------- K6: MLP1 split-K GEMM, register-prefetch pipeline ----------------
__global__ __launch_bounds__(256) void k6_mlp1(
    const float* __restrict__ A,          // [4096][2048]
    const float* __restrict__ Bw,         // [400][2048]
    float* __restrict__ part)             // [4][4096][400]
{
    __shared__ bf16 As[64 * 36];
    __shared__ bf16 Bs[64 * 36];
    int tid = threadIdx.x;
    int m0 = blockIdx.x * 64, n0 = blockIdx.y * 64, ks = blockIdx.z;
    int row = tid >> 2, seg = tid & 3;
    int w = tid >> 6, lane = tid & 63, q = lane >> 4, r15 = lane & 15;
    f32x4 z4 = {0.f, 0.f, 0.f, 0.f};
    f32x4 acc[4] = {z4, z4, z4, z4};
    const float* pA = A + (size_t)(m0 + row) * 2048 + ks * 512 + seg * 8;
    bool bvalid = (n0 + row) < 400;
    const float* pB = Bw + (size_t)(n0 + row) * 2048 + ks * 512 + seg * 8;

    f32x4 a0 = *(const f32x4*)pA;
    f32x4 a1 = *(const f32x4*)(pA + 4);
    f32x4 c0 = z4, c1 = z4;
    if (bvalid) { c0 = *(const f32x4*)pB; c1 = *(const f32x4*)(pB + 4); }

    for (int kt = 0; kt < 16; ++kt) {
        bf16x8 apk, bpk;
        apk[0] = (bf16)a0[0]; apk[1] = (bf16)a0[1]; apk[2] = (bf16)a0[2]; apk[3] = (bf16)a0[3];
        apk[4] = (bf16)a1[0]; apk[5] = (bf16)a1[1]; apk[6] = (bf16)a1[2]; apk[7] = (bf16)a1[3];
        bpk[0] = (bf16)c0[0]; bpk[1] = (bf16)c0[1]; bpk[2] = (bf16)c0[2]; bpk[3] = (bf16)c0[3];
        bpk[4] = (bf16)c1[0]; bpk[5] = (bf16)c1[1]; bpk[6] = (bf16)c1[2]; bpk[7] = (bf16)c1[3];
        __syncthreads();
        *(bf16x8*)&As[row * 36 + seg * 8] = apk;
        *(bf16x8*)&Bs[row * 36 + seg * 8] = bpk;
        __syncthreads();
        if (kt < 15) {
            pA += 32; pB += 32;
            a0 = *(const f32x4*)pA; a1 = *(const f32x4*)(pA + 4);
            if (bvalid) { c0 = *(const f32x4*)pB; c1 = *(const f32x4*)(pB + 4); }
        }
        bf16x8 a = *(const bf16x8*)&As[(w * 16 + r15) * 36 + q * 8];
#pragma unroll
        for (int nt = 0; nt < 4; ++nt) {
            bf16x8 bb = *(const bf16x8*)&Bs[(nt * 16 + r15) * 36 + q * 8];
            acc[nt] = __builtin_amdgcn_mfma_f32_16x16x32_bf16(a, bb, acc[nt], 0, 0, 0);
        }
    }
    float* pp = part + (size_t)ks * 1638400;
#pragma unroll
    for (int nt = 0; nt < 4; ++nt)
#pragma unroll
        for (int r = 0; r < 4; ++r) {
            int mm = m0 + w * 16 + q * 4 + r;
            int nn = n0 + nt * 16 + r15;
            if (nn < 400) pp[(size_t)mm * 400 + nn] = acc[nt][r];
        }
}

// ---------------- K6R: reduce 4 k-splits + bias + relu -> bf16 h1 ----------------
__global__ __launch_bounds__(256) void k6_reduce(
    const float* __restrict__ part,
    const float* __restrict__ bias,
    bf16* __restrict__ h1)
{
    int i = blockIdx.x * 256 + threadIdx.x;
    const f32x4* p = (const f32x4*)part;
    f32x4 s0 = p[i], s1v = p[i + 409600], s2v = p[i + 819200], s3v = p[i + 1228800];
    int nn = (i * 4) % 400;
    f32x4 bv = *(const f32x4*)&bias[nn];
    bf16x4 ov;
    ov[0] = (bf16)fmaxf(s0[0] + s1v[0] + s2v[0] + s3v[0] + bv[0], 0.f);
    ov[1] = (bf16)fmaxf(s0[1] + s1v[1] + s2v[1] + s3v[1] + bv[1], 0.f);
    ov[2] = (bf16)fmaxf(s0[2] + s1v[2] + s2v[2] + s3v[2] + bv[2], 0.f);
    ov[3] = (bf16)fmaxf(s0[3] + s1v[3] + s2v[3] + s3v[3] + bv[3], 0.f);
    *(bf16x4*)&h1[i * 4] = ov;
}

// ---------------- K7: MLP2  h2 = relu(h1 @ Wl2^T + bl2) ----------------
__global__ __launch_bounds__(256) void k7_mlp2(
    const bf16* __restrict__ A,           // [4096][400] bf16
    const float* __restrict__ Bw,         // [64][400] f32
    const float* __restrict__ bias,
    float* __restrict__ Cout)             // [4096][64]
{
    __shared__ bf16 As[16 * 416];
    int tid = threadIdx.x;
    int m0 = blockIdx.x * 16;
    for (int i = tid; i < 16 * 50; i += 256) {
        int rr = i / 50, cc = (i % 50) * 8;
        *(bf16x8*)&As[rr * 416 + cc] = *(const bf16x8*)(A + (size_t)(m0 + rr) * 400 + cc);
    }
    if (tid < 32) {
        int rr = tid >> 1, cc = 400 + (tid & 1) * 8;
        bf16x8 z;
#pragma unroll
        for (int k = 0; k < 8; ++k) z[k] = (bf16)0.f;
        *(bf16x8*)&As[rr * 416 + cc] = z;
    }
    __syncthreads();

    int w = tid >> 6, lane = tid & 63, q = lane >> 4, r15 = lane & 15;
    f32x4 acc = {0.f, 0.f, 0.f, 0.f};
    const float* pB = Bw + (size_t)(w * 16 + r15) * 400;
#pragma unroll 4
    for (int kt = 0; kt < 13; ++kt) {
        int k0 = kt * 32 + q * 8;
        bf16x8 a = *(const bf16x8*)&As[r15 * 416 + k0];
        bf16x8 bb;
#pragma unroll
        for (int k = 0; k < 8; ++k) bb[k] = (bf16)0.f;
        if (k0 < 400) {
            f32x4 c0 = *(const f32x4*)(pB + k0);
            f32x4 c1 = *(const f32x4*)(pB + k0 + 4);
            bb[0] = (bf16)c0[0]; bb[1] = (bf16)c0[1]; bb[2] = (bf16)c0[2]; bb[3] = (bf16)c0[3];
            bb[4] = (bf16)c1[0]; bb[5] = (bf16)c1[1]; bb[6] = (bf16)c1[2]; bb[7] = (bf16)c1[3];
        }
        acc = __builtin_amdgcn_mfma_f32_16x16x32_bf16(a, bb, acc, 0, 0, 0);
    }
#pragma unroll
    for (int r = 0; r < 4; ++r) {
        int mm = m0 + q * 4 + r;
        int nn = w * 16 + r15;
        float v = fmaxf(acc[r] + bias[nn], 0.f);
        Cout[(size_t)mm * 64 + nn] = v;
    }
}

// ---------------- K8: BN2+relu+maxpool + concat + FC ----------------
__global__ __launch_bounds__(256) void k8_final(
    const bf16* __restrict__ g2out,
    const float* __restrict__ scale2, const float* __restrict__ shift2,
    const float* __restrict__ h2,
    const float* __restrict__ Wfc,
    const float* __restrict__ bfc,
    float* __restrict__ out)
{
    __shared__ float s2s[64], sh2s[64];
    int tid = threadIdx.x;
    if (tid < 64) { s2s[tid] = scale2[tid]; sh2s[tid] = shift2[tid]; }
    __syncthreads();
    int w = tid >> 6, lane = tid & 63;
    int b = blockIdx.x * 4 + w;
    int c = lane & 31, half = lane >> 5;
    const bf16* gb = g2out + (size_t)b * 2048;
    float mx = 0.f;
    for (int i = 0; i < 32; ++i) {
        int n = half * 32 + i;
        float v = (float)gb[n * 32 + c];
        float val = fmaf(s2s[n], v, sh2s[n]);
        mx = fmaxf(mx, val);
    }
    mx = fmaxf(mx, __shfl_xor(mx, 32));
    float h2v = h2[(size_t)b * 64 + lane];
#pragma unroll
    for (int o = 0; o < 2; ++o) {
        float t = h2v * Wfc[o * 96 + 32 + lane];
        if (half == 0) t += mx * Wfc[o * 96 + c];
#pragma unroll
        for (int off = 32; off > 0; off >>= 1) t += __shfl_xor(t, off);
        if (lane == 0) out[(size_t)b * 2 + o] = t + bfc[o];
    }
}

extern "C" void kernel_launch(void* const* d_in, const int* in_sizes, int n_in,
                              void* d_out, int out_size, void* d_ws, size_t ws_size,
                              hipStream_t stream)
{
    const float* x_fp   = (const float*)d_in[0];
    const float* x_node = (const float*)d_in[1];
    const int*   edge   = (const int*)d_in[2];
    const float* W1     = (const float*)d_in[3];
    const float* b1     = (const float*)d_in[4];
    const float* g1     = (const float*)d_in[5];
    const float* be1    = (const float*)d_in[6];
    const float* W2     = (const float*)d_in[7];
    const float* b2     = (const float*)d_in[8];
    const float* g2     = (const float*)d_in[9];
    const float* be2    = (const float*)d_in[10];
    const float* Wl1    = (const float*)d_in[11];
    const float* bl1    = (const float*)d_in[12];
    const float* Wl2    = (const float*)d_in[13];
    const float* bl2    = (const float*)d_in[14];
    const float* Wfc    = (const float*)d_in[15];
    const float* bfc    = (const float*)d_in[16];
    float* out = (float*)d_out;

    char* ws = (char*)d_ws;
    bf16*  w1b     = (bf16*)(ws);                     // 13312
    bf16*  ahb     = (bf16*)(ws + 13312);             // 9216
    bf16*  w2b     = (bf16*)(ws + 22528);             // 4608
    float* scale1  = (float*)(ws + 27136);
    float* shift1  = (float*)(ws + 27392);
    float* scale2  = (float*)(ws + 27648);
    float* shift2  = (float*)(ws + 27904);
    float* part1   = (float*)(ws + 28672);            // 65536
    float* part2   = (float*)(ws + 94208);            // 65536
    char*  pool    = ws + 196608;
    // pool overlays (phase-disjoint):
    bf16*  g1out   = (bf16*)(pool);                   // 33,554,432  (k1 -> k3)
    float* part6   = (float*)(pool);                  // 26,214,400  (k6 -> k6r)
    float* h2      = (float*)(pool + 26214400);       //  1,048,576  (k7 -> k8)
    bf16*  xbq     = (bf16*)(pool + 33554432);        // 13,631,488  (conv -> k1, per quarter)
    bf16*  g2out   = (bf16*)(pool + 33554432);        // 16,777,216  (k3 -> k8)
    bf16*  h1      = (bf16*)(pool + 50331648);        //  3,276,800  (k6r -> k7)

    k0_prep<<<dim3(16), dim3(256), 0, stream>>>(edge, W1, W2, part1, ahb, w1b, w2b);
    for (int qtr = 0; qtr < 4; ++qtr) {
        int s0 = qtr * 1024;
        kx_conv<<<dim3(512), dim3(256), 0, stream>>>(x_node, xbq, s0);
        k1_gcn1<<<dim3(512), dim3(256), 0, stream>>>(xbq, w1b, ahb, b1, g1out, part1, s0);
    }
    k_bnstats<<<dim3(64), dim3(64), 0, stream>>>(part1, g1, be1, scale1, shift1,
                                                 1.f / (4096.f * 64.f));
    k3_gcn2<<<dim3(1024), dim3(256), 0, stream>>>(g1out, w2b, ahb, b2, scale1, shift1,
                                                  g2out, part2);
    k_bnstats<<<dim3(64), dim3(64), 0, stream>>>(part2, g2, be2, scale2, shift2,
                                                 1.f / (4096.f * 32.f));
    // g1out dead; k6 partials overlay it
    k6_mlp1<<<dim3(64, 7, 4), dim3(256), 0, stream>>>(x_fp, Wl1, part6);
    k6_reduce<<<dim3(1600), dim3(256), 0, stream>>>(part6, bl1, h1);
    k7_mlp2<<<dim3(256), dim3(256), 0, stream>>>(h1, Wl2, bl2, h2);
    k8_final<<<dim3(1024), dim3(256), 0, stream>>>(g2out, scale2, shift2, h2, Wfc, bfc, out);
}

// Round 6
// 315.420 us; speedup vs baseline: 1.0731x; 1.0731x over previous
//
#include <hip/hip_runtime.h>
#include <hip/hip_bf16.h>
#include <math.h>

typedef __bf16 bf16;
typedef __attribute__((ext_vector_type(8))) __bf16 bf16x8;
typedef __attribute__((ext_vector_type(4))) __bf16 bf16x4;
typedef __attribute__((ext_vector_type(4))) float f32x4;

#define EPSBN 1e-5f
#define NSLOT 128

// ---------------- K0: zero stat partials; build bf16 Ahat/W1/W2 in padded layouts ----------------
__global__ __launch_bounds__(256) void k0_prep(const int* __restrict__ edge,
    const float* __restrict__ W1, const float* __restrict__ W2,
    float* __restrict__ partials,          // 32768 floats (part1+part2)
    bf16* __restrict__ ahb,                // [64][72]
    bf16* __restrict__ w1b,                // [64][104]
    bf16* __restrict__ w2b)                // [32][72]
{
    int tid = threadIdx.x;
    for (int i = blockIdx.x * 256 + tid; i < NSLOT * 64 * 4; i += gridDim.x * 256)
        partials[i] = 0.f;
    if (blockIdx.x == 1) {
        for (int i = tid; i < 64 * 104; i += 256) {
            int n = i / 104, f = i % 104;
            w1b[i] = (bf16)((f < 67) ? W1[n * 67 + f] : 0.f);
        }
        return;
    }
    if (blockIdx.x == 2) {
        for (int i = tid; i < 32 * 72; i += 256) {
            int n = i / 72, f = i % 72;
            w2b[i] = (bf16)((f < 64) ? W2[n * 64 + f] : 0.f);
        }
        return;
    }
    if (blockIdx.x != 0) return;

    __shared__ float Ah[64 * 64];
    __shared__ int deg[64];
    __shared__ float dinv[64];
    for (int i = tid; i < 4096; i += 256) Ah[i] = 0.f;
    if (tid < 64) deg[tid] = 1;                       // self loop
    __syncthreads();
    for (int e = tid; e < 512; e += 256) atomicAdd(&deg[edge[512 + e]], 1);
    __syncthreads();
    if (tid < 64) dinv[tid] = rsqrtf((float)deg[tid]);
    __syncthreads();
    for (int e = tid; e < 512; e += 256) {
        int s = edge[e], d = edge[512 + e];
        atomicAdd(&Ah[d * 64 + s], dinv[s] * dinv[d]);
    }
    if (tid < 64) atomicAdd(&Ah[tid * 64 + tid], dinv[tid] * dinv[tid]);
    __syncthreads();
    for (int i = tid; i < 64 * 72; i += 256) {
        int n = i / 72, s = i % 72;
        ahb[i] = (bf16)((s < 64) ? Ah[n * 64 + s] : 0.f);
    }
}

// ---------------- KXC: full-batch convert x fp32 [64][67] -> padded bf16 [64][104] ----------------
// 1024 blocks x 4 samples; out chunk c (bf16x8) <-> (n=rem/13, seg=rem%13); writes coalesced.
__global__ __launch_bounds__(256) void kx_conv(const float* __restrict__ x,
    bf16* __restrict__ xb)
{
    int tid = threadIdx.x;
    const float* xs = x + (size_t)blockIdx.x * 17152;
    bf16* xo = xb + (size_t)blockIdx.x * 26624;
#pragma unroll
    for (int k = 0; k < 13; ++k) {
        int c = tid + (k << 8);                       // 0..3327
        int s = c / 832;
        int rem = c - s * 832;
        int n = rem / 13;
        int seg = rem - n * 13;
        int f0 = seg * 8;
        const float* src = xs + s * 4288 + n * 67 + f0;
        bf16x8 v;
#pragma unroll
        for (int j = 0; j < 8; ++j) {
            float t = (f0 + j < 67) ? src[j] : 0.f;
            v[j] = (bf16)t;
        }
        *(bf16x8*)(xo + (size_t)c * 8) = v;
    }
}

// ---------------- K1: GCN layer 1 — 4 samples/block (wave w -> sample), all-MFMA ----------------
// MFMA1: hT[o][n] = sum_f W1[o][f] X[n][f];  MFMA2: out[n][c] = sum_s Ahat[n][s] hT[c][s]
__global__ __launch_bounds__(256) void k1_gcn1(
    const bf16* __restrict__ xb,          // [B][64][104] padded bf16
    const bf16* __restrict__ w1b,         // [64][104]
    const bf16* __restrict__ ahb,         // [64][72]
    const float* __restrict__ b1,         // [64]
    bf16* __restrict__ g1out,             // [B][64][64]
    float* __restrict__ part1)            // [NSLOT][64][2]
{
    __shared__ bf16 sW[64 * 104];         // 13312 B
    __shared__ bf16 sX[4 * 64 * 104];     // 53248 B; per-sample 6656 bf16; overlays hT then out
    __shared__ bf16 sAh[64 * 72];         // 9216 B
    __shared__ float sstat[128];
    int tid = threadIdx.x;
    int blk = blockIdx.x;
    if (tid < 128) sstat[tid] = 0.f;

#pragma unroll
    for (int k = 0; k < 4; ++k) {
        int c = tid + (k << 8);
        if (c < 832) ((bf16x8*)sW)[c] = ((const bf16x8*)w1b)[c];
    }
#pragma unroll
    for (int k = 0; k < 3; ++k) {
        int c = tid + (k << 8);
        if (c < 576) ((bf16x8*)sAh)[c] = ((const bf16x8*)ahb)[c];
    }
    // stage X: 3328 bf16x8 chunks = 13 * 256 exactly, pure flat copies
    const bf16x8* xp = (const bf16x8*)(xb + (size_t)blk * 26624);
#pragma unroll
    for (int k = 0; k < 13; ++k) {
        int c = tid + (k << 8);
        ((bf16x8*)sX)[c] = xp[c];
    }
    __syncthreads();

    int w = tid >> 6, lane = tid & 63, q = lane >> 4, r15 = lane & 15;
    bf16* myX = sX + w * 6656;
    f32x4 z4 = {0.f, 0.f, 0.f, 0.f};
    f32x4 acc[4][4];
#pragma unroll
    for (int mt = 0; mt < 4; ++mt)
#pragma unroll
        for (int nt = 0; nt < 4; ++nt) acc[mt][nt] = z4;
#pragma unroll
    for (int kt = 0; kt < 3; ++kt) {
        bf16x8 a_[4], b_[4];
#pragma unroll
        for (int mt = 0; mt < 4; ++mt)
            a_[mt] = *(const bf16x8*)&sW[(mt * 16 + r15) * 104 + kt * 32 + q * 8];
#pragma unroll
        for (int nt = 0; nt < 4; ++nt)
            b_[nt] = *(const bf16x8*)&myX[(nt * 16 + r15) * 104 + kt * 32 + q * 8];
#pragma unroll
        for (int mt = 0; mt < 4; ++mt)
#pragma unroll
            for (int nt = 0; nt < 4; ++nt)
                acc[mt][nt] = __builtin_amdgcn_mfma_f32_16x16x32_bf16(a_[mt], b_[nt], acc[mt][nt], 0, 0, 0);
    }
    // write hT[o][n] over my X region (pitch 104); same-wave DS ordering keeps this safe
#pragma unroll
    for (int mt = 0; mt < 4; ++mt)
#pragma unroll
        for (int nt = 0; nt < 4; ++nt)
#pragma unroll
            for (int r = 0; r < 4; ++r)
                myX[(mt * 16 + q * 4 + r) * 104 + nt * 16 + r15] = (bf16)acc[mt][nt][r];

    bf16x8 ah[4][2], hb[4][2];
#pragma unroll
    for (int mt = 0; mt < 4; ++mt)
#pragma unroll
        for (int kt = 0; kt < 2; ++kt)
            ah[mt][kt] = *(const bf16x8*)&sAh[(mt * 16 + r15) * 72 + kt * 32 + q * 8];
#pragma unroll
    for (int ct = 0; ct < 4; ++ct)
#pragma unroll
        for (int kt = 0; kt < 2; ++kt)
            hb[ct][kt] = *(const bf16x8*)&myX[(ct * 16 + r15) * 104 + kt * 32 + q * 8];

    f32x4 o2[4][4];
#pragma unroll
    for (int mt = 0; mt < 4; ++mt)
#pragma unroll
        for (int ct = 0; ct < 4; ++ct) o2[mt][ct] = z4;
#pragma unroll
    for (int kt = 0; kt < 2; ++kt)
#pragma unroll
        for (int mt = 0; mt < 4; ++mt)
#pragma unroll
            for (int ct = 0; ct < 4; ++ct)
                o2[mt][ct] = __builtin_amdgcn_mfma_f32_16x16x32_bf16(ah[mt][kt], hb[ct][kt], o2[mt][ct], 0, 0, 0);

    float bv[4];
#pragma unroll
    for (int ct = 0; ct < 4; ++ct) bv[ct] = b1[ct * 16 + r15];
    // out staging over my region, pitch 72 (hb fully loaded -> safe to overwrite hT)
#pragma unroll
    for (int mt = 0; mt < 4; ++mt)
#pragma unroll
        for (int ct = 0; ct < 4; ++ct)
#pragma unroll
            for (int r = 0; r < 4; ++r)
                myX[(mt * 16 + q * 4 + r) * 72 + ct * 16 + r15] = (bf16)(o2[mt][ct][r] + bv[ct]);
    __syncthreads();

    // cooperative coalesced store + stats: 2048 16B-chunks, global offset = chunk*8 elems
    bf16* gp = g1out + (size_t)blk * 16384;
#pragma unroll
    for (int k = 0; k < 8; ++k) {
        int c = tid + (k << 8);
        int s = c >> 9, rc = c & 511, n = rc >> 3, cc = rc & 7;
        bf16x8 v = *(const bf16x8*)&sX[s * 6656 + n * 72 + cc * 8];
        ((bf16x8*)gp)[c] = v;
        float s1 = 0.f, s2 = 0.f;
#pragma unroll
        for (int j = 0; j < 8; ++j) { float f = (float)v[j]; s1 += f; s2 += f * f; }
        atomicAdd(&sstat[n * 2 + 0], s1);
        atomicAdd(&sstat[n * 2 + 1], s2);
    }
    __syncthreads();
    if (tid < 64) {
        int slot = blk & (NSLOT - 1);
        atomicAdd(&part1[(slot * 64 + tid) * 2 + 0], sstat[tid * 2 + 0]);
        atomicAdd(&part1[(slot * 64 + tid) * 2 + 1], sstat[tid * 2 + 1]);
    }
}

// ---------------- BN stats reduce ----------------
__global__ __launch_bounds__(64) void k_bnstats(
    const float* __restrict__ part,
    const float* __restrict__ gamma, const float* __restrict__ beta,
    float* __restrict__ scale, float* __restrict__ shift, float inv_count)
{
    int n = blockIdx.x, t = threadIdx.x;
    float s1 = part[(t * 64 + n) * 2] + part[((t + 64) * 64 + n) * 2];
    float s2 = part[(t * 64 + n) * 2 + 1] + part[((t + 64) * 64 + n) * 2 + 1];
#pragma unroll
    for (int o = 32; o > 0; o >>= 1) { s1 += __shfl_down(s1, o); s2 += __shfl_down(s2, o); }
    if (t == 0) {
        float mean = s1 * inv_count;
        float var = s2 * inv_count - mean * mean;
        float sc = gamma[n] * rsqrtf(var + EPSBN);
        scale[n] = sc;
        shift[n] = beta[n] - mean * sc;
    }
}

// ---------------- K3: BN1+relu -> GCN layer 2 — 4 samples/block, all-MFMA ----------------
__global__ __launch_bounds__(256) void k3_gcn2(
    const bf16* __restrict__ g1out,
    const bf16* __restrict__ w2b,         // [32][72]
    const bf16* __restrict__ ahb,         // [64][72]
    const float* __restrict__ b2,
    const float* __restrict__ scale1, const float* __restrict__ shift1,
    bf16* __restrict__ g2out,             // [B][64][32]
    float* __restrict__ part2)
{
    __shared__ bf16 sW[32 * 72];
    __shared__ bf16 sY[4 * 64 * 72];
    __shared__ bf16 sAh[64 * 72];
    __shared__ float sstat[128];
    __shared__ float ssc[64], ssh[64];
    int tid = threadIdx.x;
    int blk = blockIdx.x;
    if (tid < 128) sstat[tid] = 0.f;
    if (tid < 64) { ssc[tid] = scale1[tid]; ssh[tid] = shift1[tid]; }
#pragma unroll
    for (int k = 0; k < 2; ++k) {
        int c = tid + (k << 8);
        if (c < 288) ((bf16x8*)sW)[c] = ((const bf16x8*)w2b)[c];
    }
#pragma unroll
    for (int k = 0; k < 3; ++k) {
        int c = tid + (k << 8);
        if (c < 576) ((bf16x8*)sAh)[c] = ((const bf16x8*)ahb)[c];
    }
    __syncthreads();

    const bf16* gb = g1out + (size_t)blk * 16384;
#pragma unroll
    for (int k = 0; k < 8; ++k) {
        int c = tid + (k << 8);
        int s = c >> 9, rc = c & 511, n = rc >> 3, cc = rc & 7;
        bf16x8 g = ((const bf16x8*)gb)[c];
        float sc = ssc[n], sh = ssh[n];
        bf16x8 y;
#pragma unroll
        for (int j = 0; j < 8; ++j)
            y[j] = (bf16)fmaxf(fmaf(sc, (float)g[j], sh), 0.f);
        *(bf16x8*)&sY[s * 4608 + n * 72 + cc * 8] = y;
    }
    __syncthreads();

    int w = tid >> 6, lane = tid & 63, q = lane >> 4, r15 = lane & 15;
    bf16* myY = sY + w * 4608;
    f32x4 z4 = {0.f, 0.f, 0.f, 0.f};
    f32x4 acc[2][4];
#pragma unroll
    for (int mt = 0; mt < 2; ++mt)
#pragma unroll
        for (int nt = 0; nt < 4; ++nt) acc[mt][nt] = z4;
#pragma unroll
    for (int kt = 0; kt < 2; ++kt) {
        bf16x8 a_[2], b_[4];
#pragma unroll
        for (int mt = 0; mt < 2; ++mt)
            a_[mt] = *(const bf16x8*)&sW[(mt * 16 + r15) * 72 + kt * 32 + q * 8];
#pragma unroll
        for (int nt = 0; nt < 4; ++nt)
            b_[nt] = *(const bf16x8*)&myY[(nt * 16 + r15) * 72 + kt * 32 + q * 8];
#pragma unroll
        for (int mt = 0; mt < 2; ++mt)
#pragma unroll
            for (int nt = 0; nt < 4; ++nt)
                acc[mt][nt] = __builtin_amdgcn_mfma_f32_16x16x32_bf16(a_[mt], b_[nt], acc[mt][nt], 0, 0, 0);
    }
#pragma unroll
    for (int mt = 0; mt < 2; ++mt)
#pragma unroll
        for (int nt = 0; nt < 4; ++nt)
#pragma unroll
            for (int r = 0; r < 4; ++r)
                myY[(mt * 16 + q * 4 + r) * 72 + nt * 16 + r15] = (bf16)acc[mt][nt][r];

    bf16x8 ah[4][2], hb[2][2];
#pragma unroll
    for (int mt = 0; mt < 4; ++mt)
#pragma unroll
        for (int kt = 0; kt < 2; ++kt)
            ah[mt][kt] = *(const bf16x8*)&sAh[(mt * 16 + r15) * 72 + kt * 32 + q * 8];
#pragma unroll
    for (int ct = 0; ct < 2; ++ct)
#pragma unroll
        for (int kt = 0; kt < 2; ++kt)
            hb[ct][kt] = *(const bf16x8*)&myY[(ct * 16 + r15) * 72 + kt * 32 + q * 8];

    f32x4 o2[4][2];
#pragma unroll
    for (int mt = 0; mt < 4; ++mt)
#pragma unroll
        for (int ct = 0; ct < 2; ++ct) o2[mt][ct] = z4;
#pragma unroll
    for (int kt = 0; kt < 2; ++kt)
#pragma unroll
        for (int mt = 0; mt < 4; ++mt)
#pragma unroll
            for (int ct = 0; ct < 2; ++ct)
                o2[mt][ct] = __builtin_amdgcn_mfma_f32_16x16x32_bf16(ah[mt][kt], hb[ct][kt], o2[mt][ct], 0, 0, 0);

    float bv[2];
#pragma unroll
    for (int ct = 0; ct < 2; ++ct) bv[ct] = b2[ct * 16 + r15];
#pragma unroll
    for (int mt = 0; mt < 4; ++mt)
#pragma unroll
        for (int ct = 0; ct < 2; ++ct)
#pragma unroll
            for (int r = 0; r < 4; ++r)
                myY[(mt * 16 + q * 4 + r) * 40 + ct * 16 + r15] = (bf16)(o2[mt][ct][r] + bv[ct]);
    __syncthreads();

    bf16* gp = g2out + (size_t)blk * 8192;
#pragma unroll
    for (int k = 0; k < 4; ++k) {
        int c = tid + (k << 8);
        int s = c >> 8, rc = c & 255, n = rc >> 2, cc = rc & 3;
        bf16x8 v = *(const bf16x8*)&sY[s * 4608 + n * 40 + cc * 8];
        ((bf16x8*)gp)[c] = v;
        float s1 = 0.f, s2 = 0.f;
#pragma unroll
        for (int j = 0; j < 8; ++j) { float f = (float)v[j]; s1 += f; s2 += f * f; }
        atomicAdd(&sstat[n * 2 + 0], s1);
        atomicAdd(&sstat[n * 2 + 1], s2);
    }
    __syncthreads();
    if (tid < 64) {
        int slot = blk & (NSLOT - 1);
        atomicAdd(&part2[(slot * 64 + tid) * 2 + 0], sstat[tid * 2 + 0]);
        atomicAdd(&part2[(slot * 64 + tid) * 2 + 1], sstat[tid * 2 + 1]);
    }
}

// ---------------- K6: MLP1 split-K GEMM, register-prefetch pipeline ----------------
__global__ __launch_bounds__(256) void k6_mlp1(
    const float* __restrict__ A,          // [4096][2048]
    const float* __restrict__ Bw,         // [400][2048]
    float* __restrict__ part)             // [4][4096][400]
{
    __shared__ bf16 As[64 * 36];
    __shared__ bf16 Bs[64 * 36];
    int tid = threadIdx.x;
    int m0 = blockIdx.x * 64, n0 = blockIdx.y * 64, ks = blockIdx.z;
    int row = tid >> 2, seg = tid & 3;
    int w = tid >> 6, lane = tid & 63, q = lane >> 4, r15 = lane & 15;
    f32x4 z4 = {0.f, 0.f, 0.f, 0.f};
    f32x4 acc[4] = {z4, z4, z4, z4};
    const float* pA = A + (size_t)(m0 + row) * 2048 + ks * 512 + seg * 8;
    bool bvalid = (n0 + row) < 400;
    const float* pB = Bw + (size_t)(n0 + row) * 2048 + ks * 512 + seg * 8;

    f32x4 a0 = *(const f32x4*)pA;
    f32x4 a1 = *(const f32x4*)(pA + 4);
    f32x4 c0 = z4, c1 = z4;
    if (bvalid) { c0 = *(const f32x4*)pB; c1 = *(const f32x4*)(pB + 4); }

    for (int kt = 0; kt < 16; ++kt) {
        bf16x8 apk, bpk;
        apk[0] = (bf16)a0[0]; apk[1] = (bf16)a0[1]; apk[2] = (bf16)a0[2]; apk[3] = (bf16)a0[3];
        apk[4] = (bf16)a1[0]; apk[5] = (bf16)a1[1]; apk[6] = (bf16)a1[2]; apk[7] = (bf16)a1[3];
        bpk[0] = (bf16)c0[0]; bpk[1] = (bf16)c0[1]; bpk[2] = (bf16)c0[2]; bpk[3] = (bf16)c0[3];
        bpk[4] = (bf16)c1[0]; bpk[5] = (bf16)c1[1]; bpk[6] = (bf16)c1[2]; bpk[7] = (bf16)c1[3];
        __syncthreads();
        *(bf16x8*)&As[row * 36 + seg * 8] = apk;
        *(bf16x8*)&Bs[row * 36 + seg * 8] = bpk;
        __syncthreads();
        if (kt < 15) {
            pA += 32; pB += 32;
            a0 = *(const f32x4*)pA; a1 = *(const f32x4*)(pA + 4);
            if (bvalid) { c0 = *(const f32x4*)pB; c1 = *(const f32x4*)(pB + 4); }
        }
        bf16x8 a = *(const bf16x8*)&As[(w * 16 + r15) * 36 + q * 8];
#pragma unroll
        for (int nt = 0; nt < 4; ++nt) {
            bf16x8 bb = *(const bf16x8*)&Bs[(nt * 16 + r15) * 36 + q * 8];
            acc[nt] = __builtin_amdgcn_mfma_f32_16x16x32_bf16(a, bb, acc[nt], 0, 0, 0);
        }
    }
    float* pp = part + (size_t)ks * 1638400;
#pragma unroll
    for (int nt = 0; nt < 4; ++nt)
#pragma unroll
        for (int r = 0; r < 4; ++r) {
            int mm = m0 + w * 16 + q * 4 + r;
            int nn = n0 + nt * 16 + r15;
            if (nn < 400) pp[(size_t)mm * 400 + nn] = acc[nt][r];
        }
}

// ---------------- K6R: reduce 4 k-splits + bias + relu -> bf16 h1 ----------------
__global__ __launch_bounds__(256) void k6_reduce(
    const float* __restrict__ part,
    const float* __restrict__ bias,
    bf16* __restrict__ h1)
{
    int i = blockIdx.x * 256 + threadIdx.x;
    const f32x4* p = (const f32x4*)part;
    f32x4 s0 = p[i], s1v = p[i + 409600], s2v = p[i + 819200], s3v = p[i + 1228800];
    int nn = (i * 4) % 400;
    f32x4 bv = *(const f32x4*)&bias[nn];
    bf16x4 ov;
    ov[0] = (bf16)fmaxf(s0[0] + s1v[0] + s2v[0] + s3v[0] + bv[0], 0.f);
    ov[1] = (bf16)fmaxf(s0[1] + s1v[1] + s2v[1] + s3v[1] + bv[1], 0.f);
    ov[2] = (bf16)fmaxf(s0[2] + s1v[2] + s2v[2] + s3v[2] + bv[2], 0.f);
    ov[3] = (bf16)fmaxf(s0[3] + s1v[3] + s2v[3] + s3v[3] + bv[3], 0.f);
    *(bf16x4*)&h1[i * 4] = ov;
}

// ---------------- K7: MLP2  h2 = relu(h1 @ Wl2^T + bl2) ----------------
__global__ __launch_bounds__(256) void k7_mlp2(
    const bf16* __restrict__ A,           // [4096][400] bf16
    const float* __restrict__ Bw,         // [64][400] f32
    const float* __restrict__ bias,
    float* __restrict__ Cout)             // [4096][64]
{
    __shared__ bf16 As[16 * 416];
    int tid = threadIdx.x;
    int m0 = blockIdx.x * 16;
    for (int i = tid; i < 16 * 50; i += 256) {
        int rr = i / 50, cc = (i % 50) * 8;
        *(bf16x8*)&As[rr * 416 + cc] = *(const bf16x8*)(A + (size_t)(m0 + rr) * 400 + cc);
    }
    if (tid < 32) {
        int rr = tid >> 1, cc = 400 + (tid & 1) * 8;
        bf16x8 z;
#pragma unroll
        for (int k = 0; k < 8; ++k) z[k] = (bf16)0.f;
        *(bf16x8*)&As[rr * 416 + cc] = z;
    }
    __syncthreads();

    int w = tid >> 6, lane = tid & 63, q = lane >> 4, r15 = lane & 15;
    f32x4 acc = {0.f, 0.f, 0.f, 0.f};
    const float* pB = Bw + (size_t)(w * 16 + r15) * 400;
#pragma unroll 4
    for (int kt = 0; kt < 13; ++kt) {
        int k0 = kt * 32 + q * 8;
        bf16x8 a = *(const bf16x8*)&As[r15 * 416 + k0];
        bf16x8 bb;
#pragma unroll
        for (int k = 0; k < 8; ++k) bb[k] = (bf16)0.f;
        if (k0 < 400) {
            f32x4 c0 = *(const f32x4*)(pB + k0);
            f32x4 c1 = *(const f32x4*)(pB + k0 + 4);
            bb[0] = (bf16)c0[0]; bb[1] = (bf16)c0[1]; bb[2] = (bf16)c0[2]; bb[3] = (bf16)c0[3];
            bb[4] = (bf16)c1[0]; bb[5] = (bf16)c1[1]; bb[6] = (bf16)c1[2]; bb[7] = (bf16)c1[3];
        }
        acc = __builtin_amdgcn_mfma_f32_16x16x32_bf16(a, bb, acc, 0, 0, 0);
    }
#pragma unroll
    for (int r = 0; r < 4; ++r) {
        int mm = m0 + q * 4 + r;
        int nn = w * 16 + r15;
        float v = fmaxf(acc[r] + bias[nn], 0.f);
        Cout[(size_t)mm * 64 + nn] = v;
    }
}

// ---------------- K8: BN2+relu+maxpool + concat + FC ----------------
__global__ __launch_bounds__(256) void k8_final(
    const bf16* __restrict__ g2out,
    const float* __restrict__ scale2, const float* __restrict__ shift2,
    const float* __restrict__ h2,
    const float* __restrict__ Wfc,
    const float* __restrict__ bfc,
    float* __restrict__ out)
{
    __shared__ float s2s[64], sh2s[64];
    int tid = threadIdx.x;
    if (tid < 64) { s2s[tid] = scale2[tid]; sh2s[tid] = shift2[tid]; }
    __syncthreads();
    int w = tid >> 6, lane = tid & 63;
    int b = blockIdx.x * 4 + w;
    int c = lane & 31, half = lane >> 5;
    const bf16* gb = g2out + (size_t)b * 2048;
    float mx = 0.f;
    for (int i = 0; i < 32; ++i) {
        int n = half * 32 + i;
        float v = (float)gb[n * 32 + c];
        float val = fmaf(s2s[n], v, sh2s[n]);
        mx = fmaxf(mx, val);
    }
    mx = fmaxf(mx, __shfl_xor(mx, 32));
    float h2v = h2[(size_t)b * 64 + lane];
#pragma unroll
    for (int o = 0; o < 2; ++o) {
        float t = h2v * Wfc[o * 96 + 32 + lane];
        if (half == 0) t += mx * Wfc[o * 96 + c];
#pragma unroll
        for (int off = 32; off > 0; off >>= 1) t += __shfl_xor(t, off);
        if (lane == 0) out[(size_t)b * 2 + o] = t + bfc[o];
    }
}

extern "C" void kernel_launch(void* const* d_in, const int* in_sizes, int n_in,
                              void* d_out, int out_size, void* d_ws, size_t ws_size,
                              hipStream_t stream)
{
    const float* x_fp   = (const float*)d_in[0];
    const float* x_node = (const float*)d_in[1];
    const int*   edge   = (const int*)d_in[2];
    const float* W1     = (const float*)d_in[3];
    const float* b1     = (const float*)d_in[4];
    const float* g1     = (const float*)d_in[5];
    const float* be1    = (const float*)d_in[6];
    const float* W2     = (const float*)d_in[7];
    const float* b2     = (const float*)d_in[8];
    const float* g2     = (const float*)d_in[9];
    const float* be2    = (const float*)d_in[10];
    const float* Wl1    = (const float*)d_in[11];
    const float* bl1    = (const float*)d_in[12];
    const float* Wl2    = (const float*)d_in[13];
    const float* bl2    = (const float*)d_in[14];
    const float* Wfc    = (const float*)d_in[15];
    const float* bfc    = (const float*)d_in[16];
    float* out = (float*)d_out;

    // ws_size observed >= 268 MiB (harness 0xAA fill of 281 MB) -> disjoint layout, no overlays
    char* ws = (char*)d_ws;
    bf16*  w1b     = (bf16*)(ws);                     // 13312
    bf16*  ahb     = (bf16*)(ws + 13312);             // 9216
    bf16*  w2b     = (bf16*)(ws + 22528);             // 4608
    float* scale1  = (float*)(ws + 27136);
    float* shift1  = (float*)(ws + 27392);
    float* scale2  = (float*)(ws + 27648);
    float* shift2  = (float*)(ws + 27904);
    float* part1   = (float*)(ws + 28672);            // 65536
    float* part2   = (float*)(ws + 94208);            // 65536
    char*  pool    = ws + 196608;
    bf16*  xb      = (bf16*)(pool);                   // 54,525,952
    bf16*  g1out   = (bf16*)(pool + 54525952ull);     // 33,554,432
    bf16*  g2out   = (bf16*)(pool + 88080384ull);     // 16,777,216
    float* part6   = (float*)(pool + 104857600ull);   // 26,214,400
    bf16*  h1      = (bf16*)(pool + 131072000ull);    //  3,276,800
    float* h2      = (float*)(pool + 134348800ull);   //  1,048,576  (pool total ~135.4 MB)

    k0_prep<<<dim3(16), dim3(256), 0, stream>>>(edge, W1, W2, part1, ahb, w1b, w2b);
    kx_conv<<<dim3(1024), dim3(256), 0, stream>>>(x_node, xb);
    k1_gcn1<<<dim3(1024), dim3(256), 0, stream>>>(xb, w1b, ahb, b1, g1out, part1);
    k_bnstats<<<dim3(64), dim3(64), 0, stream>>>(part1, g1, be1, scale1, shift1,
                                                 1.f / (4096.f * 64.f));
    k3_gcn2<<<dim3(1024), dim3(256), 0, stream>>>(g1out, w2b, ahb, b2, scale1, shift1,
                                                  g2out, part2);
    k_bnstats<<<dim3(64), dim3(64), 0, stream>>>(part2, g2, be2, scale2, shift2,
                                                 1.f / (4096.f * 32.f));
    k6_mlp1<<<dim3(64, 7, 4), dim3(256), 0, stream>>>(x_fp, Wl1, part6);
    k6_reduce<<<dim3(1600), dim3(256), 0, stream>>>(part6, bl1, h1);
    k7_mlp2<<<dim3(256), dim3(256), 0, stream>>>(h1, Wl2, bl2, h2);
    k8_final<<<dim3(1024), dim3(256), 0, stream>>>(g2out, scale2, shift2, h2, Wfc, bfc, out);
}

// Round 7
// 274.966 us; speedup vs baseline: 1.2310x; 1.1471x over previous
//
#include <hip/hip_runtime.h>
#include <hip/hip_bf16.h>
#include <math.h>

typedef __bf16 bf16;
typedef __attribute__((ext_vector_type(8))) __bf16 bf16x8;
typedef __attribute__((ext_vector_type(4))) __bf16 bf16x4;
typedef __attribute__((ext_vector_type(4))) float f32x4;

#define EPSBN 1e-5f
#define NSLOT 128

// ---------------- K0: zero stat partials; build bf16 Ahat/W1/W2 in padded layouts ----------------
__global__ __launch_bounds__(256) void k0_prep(const int* __restrict__ edge,
    const float* __restrict__ W1, const float* __restrict__ W2,
    float* __restrict__ partials,          // 32768 floats (part1+part2)
    bf16* __restrict__ ahb,                // [64][72]
    bf16* __restrict__ w1b,                // [64][104]
    bf16* __restrict__ w2b)                // [32][72]
{
    int tid = threadIdx.x;
    for (int i = blockIdx.x * 256 + tid; i < NSLOT * 64 * 4; i += gridDim.x * 256)
        partials[i] = 0.f;
    if (blockIdx.x == 1) {
        for (int i = tid; i < 64 * 104; i += 256) {
            int n = i / 104, f = i % 104;
            w1b[i] = (bf16)((f < 67) ? W1[n * 67 + f] : 0.f);
        }
        return;
    }
    if (blockIdx.x == 2) {
        for (int i = tid; i < 32 * 72; i += 256) {
            int n = i / 72, f = i % 72;
            w2b[i] = (bf16)((f < 64) ? W2[n * 64 + f] : 0.f);
        }
        return;
    }
    if (blockIdx.x != 0) return;

    __shared__ float Ah[64 * 64];
    __shared__ int deg[64];
    __shared__ float dinv[64];
    for (int i = tid; i < 4096; i += 256) Ah[i] = 0.f;
    if (tid < 64) deg[tid] = 1;                       // self loop
    __syncthreads();
    for (int e = tid; e < 512; e += 256) atomicAdd(&deg[edge[512 + e]], 1);
    __syncthreads();
    if (tid < 64) dinv[tid] = rsqrtf((float)deg[tid]);
    __syncthreads();
    for (int e = tid; e < 512; e += 256) {
        int s = edge[e], d = edge[512 + e];
        atomicAdd(&Ah[d * 64 + s], dinv[s] * dinv[d]);
    }
    if (tid < 64) atomicAdd(&Ah[tid * 64 + tid], dinv[tid] * dinv[tid]);
    __syncthreads();
    for (int i = tid; i < 64 * 72; i += 256) {
        int n = i / 72, s = i % 72;
        ahb[i] = (bf16)((s < 64) ? Ah[n * 64 + s] : 0.f);
    }
}

// ---------------- K1: GCN layer 1 — 1 sample/block, 4 waves split M, all-MFMA ----------------
// Stage fp32 coalesced -> LDS repack to padded bf16 -> MFMA1 (W1) -> MFMA2 (Ahat) -> store+stats.
__global__ __launch_bounds__(256) void k1_gcn1(
    const float* __restrict__ x,          // [B][64][67] fp32
    const bf16* __restrict__ w1b,         // [64][104]
    const bf16* __restrict__ ahb,         // [64][72]
    const float* __restrict__ b1,         // [64]
    bf16* __restrict__ g1out,             // [B][64][64]
    float* __restrict__ part1)            // [NSLOT][64][2]
{
    __shared__ float sXf[4288];           // 17152 B raw fp32 sample
    __shared__ bf16 sX[64 * 104];         // 13312 B padded bf16; reused for hT (pitch 104) then out (pitch 72)
    __shared__ float sstat[128];
    int tid = threadIdx.x;
    int blk = blockIdx.x;
    if (tid < 128) sstat[tid] = 0.f;

    // 1) coalesced fp32 load: 1072 consecutive f32x4 chunks
    const f32x4* xp = (const f32x4*)(x + (size_t)blk * 4288);
#pragma unroll
    for (int k = 0; k < 5; ++k) {
        int c = tid + (k << 8);
        if (c < 1072) ((f32x4*)sXf)[c] = xp[c];
    }

    int w = tid >> 6, lane = tid & 63, q = lane >> 4, r15 = lane & 15;
    // A-frags straight from global (shared across all blocks -> L1/L2-hot)
    bf16x8 aw[3], ah[2];
#pragma unroll
    for (int kt = 0; kt < 3; ++kt)
        aw[kt] = *(const bf16x8*)&w1b[(w * 16 + r15) * 104 + kt * 32 + q * 8];
#pragma unroll
    for (int kt = 0; kt < 2; ++kt)
        ah[kt] = *(const bf16x8*)&ahb[(w * 16 + r15) * 72 + kt * 32 + q * 8];
    __syncthreads();

    // 2) repack LDS fp32 -> padded bf16 [64][104]; lane handles row n = tid&63 (67-dword
    //    stride across lanes -> conflict-free), sub-group sg = tid>>6 covers segs sg, sg+4, sg+8, sg+12.
    {
        int n = tid & 63, sg = tid >> 6;
#pragma unroll
        for (int i = 0; i < 4; ++i) {
            int seg = sg + 4 * i;
            if (seg < 13) {
                int f0 = seg * 8;
                bf16x8 v;
#pragma unroll
                for (int j = 0; j < 8; ++j) {
                    int f = f0 + j;
                    float t = (f < 67) ? sXf[n * 67 + f] : 0.f;
                    v[j] = (bf16)t;
                }
                *(bf16x8*)&sX[n * 104 + f0] = v;
            }
        }
    }
    __syncthreads();

    // 3) MFMA1: hT[o][n], wave w computes o-rows w*16..w*16+15
    f32x4 z4 = {0.f, 0.f, 0.f, 0.f};
    f32x4 acc[4] = {z4, z4, z4, z4};
#pragma unroll
    for (int kt = 0; kt < 3; ++kt) {
        bf16x8 b_[4];
#pragma unroll
        for (int nt = 0; nt < 4; ++nt)
            b_[nt] = *(const bf16x8*)&sX[(nt * 16 + r15) * 104 + kt * 32 + q * 8];
#pragma unroll
        for (int nt = 0; nt < 4; ++nt)
            acc[nt] = __builtin_amdgcn_mfma_f32_16x16x32_bf16(aw[kt], b_[nt], acc[nt], 0, 0, 0);
    }
    __syncthreads();                                  // all X reads done
    // write hT (pitch 104): row o = w*16+q*4+r, col n = nt*16+r15
#pragma unroll
    for (int nt = 0; nt < 4; ++nt)
#pragma unroll
        for (int r = 0; r < 4; ++r)
            sX[(w * 16 + q * 4 + r) * 104 + nt * 16 + r15] = (bf16)acc[nt][r];
    __syncthreads();

    // 4) MFMA2: out[n][c] = sum_s Ah[n][s] hT[c][s]; wave w computes n-rows w*16..
    f32x4 o2[4] = {z4, z4, z4, z4};
#pragma unroll
    for (int kt = 0; kt < 2; ++kt) {
        bf16x8 hbv[4];
#pragma unroll
        for (int ct = 0; ct < 4; ++ct)
            hbv[ct] = *(const bf16x8*)&sX[(ct * 16 + r15) * 104 + kt * 32 + q * 8];
#pragma unroll
        for (int ct = 0; ct < 4; ++ct)
            o2[ct] = __builtin_amdgcn_mfma_f32_16x16x32_bf16(ah[kt], hbv[ct], o2[ct], 0, 0, 0);
    }
    float bv[4];
#pragma unroll
    for (int ct = 0; ct < 4; ++ct) bv[ct] = b1[ct * 16 + r15];
    __syncthreads();                                  // hT reads done before overwrite
    // out staging pitch 72: row n = w*16+q*4+r, col c = ct*16+r15
#pragma unroll
    for (int ct = 0; ct < 4; ++ct)
#pragma unroll
        for (int r = 0; r < 4; ++r)
            sX[(w * 16 + q * 4 + r) * 72 + ct * 16 + r15] = (bf16)(o2[ct][r] + bv[ct]);
    __syncthreads();

    // 5) coalesced store (512 16B chunks) + stats
    bf16* gp = g1out + (size_t)blk * 4096;
#pragma unroll
    for (int k = 0; k < 2; ++k) {
        int c = tid + (k << 8);
        int n = c >> 3, cc = c & 7;
        bf16x8 v = *(const bf16x8*)&sX[n * 72 + cc * 8];
        ((bf16x8*)gp)[c] = v;
        float s1 = 0.f, s2 = 0.f;
#pragma unroll
        for (int j = 0; j < 8; ++j) { float f = (float)v[j]; s1 += f; s2 += f * f; }
        atomicAdd(&sstat[n * 2 + 0], s1);
        atomicAdd(&sstat[n * 2 + 1], s2);
    }
    __syncthreads();
    if (tid < 64) {
        int slot = blk & (NSLOT - 1);
        atomicAdd(&part1[(slot * 64 + tid) * 2 + 0], sstat[tid * 2 + 0]);
        atomicAdd(&part1[(slot * 64 + tid) * 2 + 1], sstat[tid * 2 + 1]);
    }
}

// ---------------- BN stats reduce ----------------
__global__ __launch_bounds__(64) void k_bnstats(
    const float* __restrict__ part,
    const float* __restrict__ gamma, const float* __restrict__ beta,
    float* __restrict__ scale, float* __restrict__ shift, float inv_count)
{
    int n = blockIdx.x, t = threadIdx.x;
    float s1 = part[(t * 64 + n) * 2] + part[((t + 64) * 64 + n) * 2];
    float s2 = part[(t * 64 + n) * 2 + 1] + part[((t + 64) * 64 + n) * 2 + 1];
#pragma unroll
    for (int o = 32; o > 0; o >>= 1) { s1 += __shfl_down(s1, o); s2 += __shfl_down(s2, o); }
    if (t == 0) {
        float mean = s1 * inv_count;
        float var = s2 * inv_count - mean * mean;
        float sc = gamma[n] * rsqrtf(var + EPSBN);
        scale[n] = sc;
        shift[n] = beta[n] - mean * sc;
    }
}

// ---------------- K3: BN1+relu -> GCN layer 2 — 1 sample/block, 4 waves, all-MFMA ----------------
__global__ __launch_bounds__(256) void k3_gcn2(
    const bf16* __restrict__ g1out,       // [B][64][64]
    const bf16* __restrict__ w2b,         // [32][72]
    const bf16* __restrict__ ahb,         // [64][72]
    const float* __restrict__ b2,
    const float* __restrict__ scale1, const float* __restrict__ shift1,
    bf16* __restrict__ g2out,             // [B][64][32]
    float* __restrict__ part2)
{
    __shared__ bf16 sY[64 * 72];          // 9216 B
    __shared__ bf16 sH[32 * 72];          // 4608 B
    __shared__ bf16 sO[64 * 40];          // 5120 B
    __shared__ float ssc[64], ssh[64];
    __shared__ float sstat[128];
    int tid = threadIdx.x;
    int blk = blockIdx.x;
    if (tid < 128) sstat[tid] = 0.f;
    if (tid < 64) { ssc[tid] = scale1[tid]; ssh[tid] = shift1[tid]; }

    int w = tid >> 6, lane = tid & 63, q = lane >> 4, r15 = lane & 15;
    bf16x8 aw[2][2], ah[2];
#pragma unroll
    for (int mt = 0; mt < 2; ++mt)
#pragma unroll
        for (int kt = 0; kt < 2; ++kt)
            aw[mt][kt] = *(const bf16x8*)&w2b[(mt * 16 + r15) * 72 + kt * 32 + q * 8];
#pragma unroll
    for (int kt = 0; kt < 2; ++kt)
        ah[kt] = *(const bf16x8*)&ahb[(w * 16 + r15) * 72 + kt * 32 + q * 8];
    __syncthreads();                                  // ssc/ssh ready

    // stage Y = relu(scale*g1+shift): 512 coalesced chunks
    const bf16* gb = g1out + (size_t)blk * 4096;
#pragma unroll
    for (int k = 0; k < 2; ++k) {
        int c = tid + (k << 8);
        int n = c >> 3, cc = c & 7;
        bf16x8 g = ((const bf16x8*)gb)[c];
        float sc = ssc[n], sh = ssh[n];
        bf16x8 y;
#pragma unroll
        for (int j = 0; j < 8; ++j)
            y[j] = (bf16)fmaxf(fmaf(sc, (float)g[j], sh), 0.f);
        *(bf16x8*)&sY[n * 72 + cc * 8] = y;
    }
    __syncthreads();

    // MFMA1: hT[o][n], wave w handles n-cols w*16.. (b-frag from its own Y rows)
    f32x4 z4 = {0.f, 0.f, 0.f, 0.f};
    f32x4 acc[2] = {z4, z4};
#pragma unroll
    for (int kt = 0; kt < 2; ++kt) {
        bf16x8 b_ = *(const bf16x8*)&sY[(w * 16 + r15) * 72 + kt * 32 + q * 8];
#pragma unroll
        for (int mt = 0; mt < 2; ++mt)
            acc[mt] = __builtin_amdgcn_mfma_f32_16x16x32_bf16(aw[mt][kt], b_, acc[mt], 0, 0, 0);
    }
    // write hT (separate buffer -> no pre-sync needed): row o = mt*16+q*4+r, col n = w*16+r15
#pragma unroll
    for (int mt = 0; mt < 2; ++mt)
#pragma unroll
        for (int r = 0; r < 4; ++r)
            sH[(mt * 16 + q * 4 + r) * 72 + w * 16 + r15] = (bf16)acc[mt][r];
    __syncthreads();

    // MFMA2: out[n][c], wave w handles n-rows w*16..
    f32x4 o2[2] = {z4, z4};
#pragma unroll
    for (int kt = 0; kt < 2; ++kt) {
        bf16x8 hbv[2];
#pragma unroll
        for (int ct = 0; ct < 2; ++ct)
            hbv[ct] = *(const bf16x8*)&sH[(ct * 16 + r15) * 72 + kt * 32 + q * 8];
#pragma unroll
        for (int ct = 0; ct < 2; ++ct)
            o2[ct] = __builtin_amdgcn_mfma_f32_16x16x32_bf16(ah[kt], hbv[ct], o2[ct], 0, 0, 0);
    }
    float bv[2];
#pragma unroll
    for (int ct = 0; ct < 2; ++ct) bv[ct] = b2[ct * 16 + r15];
#pragma unroll
    for (int ct = 0; ct < 2; ++ct)
#pragma unroll
        for (int r = 0; r < 4; ++r)
            sO[(w * 16 + q * 4 + r) * 40 + ct * 16 + r15] = (bf16)(o2[ct][r] + bv[ct]);
    __syncthreads();

    // store 256 chunks (1/thread) + stats
    bf16* gp = g2out + (size_t)blk * 2048;
    {
        int c = tid;
        int n = c >> 2, cc = c & 3;
        bf16x8 v = *(const bf16x8*)&sO[n * 40 + cc * 8];
        ((bf16x8*)gp)[c] = v;
        float s1 = 0.f, s2 = 0.f;
#pragma unroll
        for (int j = 0; j < 8; ++j) { float f = (float)v[j]; s1 += f; s2 += f * f; }
        atomicAdd(&sstat[n * 2 + 0], s1);
        atomicAdd(&sstat[n * 2 + 1], s2);
    }
    __syncthreads();
    if (tid < 64) {
        int slot = blk & (NSLOT - 1);
        atomicAdd(&part2[(slot * 64 + tid) * 2 + 0], sstat[tid * 2 + 0]);
        atomicAdd(&part2[(slot * 64 + tid) * 2 + 1], sstat[tid * 2 + 1]);
    }
}

// ---------------- K6: MLP1 split-K GEMM, register-prefetch pipeline ----------------
__global__ __launch_bounds__(256) void k6_mlp1(
    const float* __restrict__ A,          // [4096][2048]
    const float* __restrict__ Bw,         // [400][2048]
    float* __restrict__ part)             // [4][4096][400]
{
    __shared__ bf16 As[64 * 36];
    __shared__ bf16 Bs[64 * 36];
    int tid = threadIdx.x;
    int m0 = blockIdx.x * 64, n0 = blockIdx.y * 64, ks = blockIdx.z;
    int row = tid >> 2, seg = tid & 3;
    int w = tid >> 6, lane = tid & 63, q = lane >> 4, r15 = lane & 15;
    f32x4 z4 = {0.f, 0.f, 0.f, 0.f};
    f32x4 acc[4] = {z4, z4, z4, z4};
    const float* pA = A + (size_t)(m0 + row) * 2048 + ks * 512 + seg * 8;
    bool bvalid = (n0 + row) < 400;
    const float* pB = Bw + (size_t)(n0 + row) * 2048 + ks * 512 + seg * 8;

    f32x4 a0 = *(const f32x4*)pA;
    f32x4 a1 = *(const f32x4*)(pA + 4);
    f32x4 c0 = z4, c1 = z4;
    if (bvalid) { c0 = *(const f32x4*)pB; c1 = *(const f32x4*)(pB + 4); }

    for (int kt = 0; kt < 16; ++kt) {
        bf16x8 apk, bpk;
        apk[0] = (bf16)a0[0]; apk[1] = (bf16)a0[1]; apk[2] = (bf16)a0[2]; apk[3] = (bf16)a0[3];
        apk[4] = (bf16)a1[0]; apk[5] = (bf16)a1[1]; apk[6] = (bf16)a1[2]; apk[7] = (bf16)a1[3];
        bpk[0] = (bf16)c0[0]; bpk[1] = (bf16)c0[1]; bpk[2] = (bf16)c0[2]; bpk[3] = (bf16)c0[3];
        bpk[4] = (bf16)c1[0]; bpk[5] = (bf16)c1[1]; bpk[6] = (bf16)c1[2]; bpk[7] = (bf16)c1[3];
        __syncthreads();
        *(bf16x8*)&As[row * 36 + seg * 8] = apk;
        *(bf16x8*)&Bs[row * 36 + seg * 8] = bpk;
        __syncthreads();
        if (kt < 15) {
            pA += 32; pB += 32;
            a0 = *(const f32x4*)pA; a1 = *(const f32x4*)(pA + 4);
            if (bvalid) { c0 = *(const f32x4*)pB; c1 = *(const f32x4*)(pB + 4); }
        }
        bf16x8 a = *(const bf16x8*)&As[(w * 16 + r15) * 36 + q * 8];
#pragma unroll
        for (int nt = 0; nt < 4; ++nt) {
            bf16x8 bb = *(const bf16x8*)&Bs[(nt * 16 + r15) * 36 + q * 8];
            acc[nt] = __builtin_amdgcn_mfma_f32_16x16x32_bf16(a, bb, acc[nt], 0, 0, 0);
        }
    }
    float* pp = part + (size_t)ks * 1638400;
#pragma unroll
    for (int nt = 0; nt < 4; ++nt)
#pragma unroll
        for (int r = 0; r < 4; ++r) {
            int mm = m0 + w * 16 + q * 4 + r;
            int nn = n0 + nt * 16 + r15;
            if (nn < 400) pp[(size_t)mm * 400 + nn] = acc[nt][r];
        }
}

// ---------------- K6R: reduce 4 k-splits + bias + relu -> bf16 h1 ----------------
__global__ __launch_bounds__(256) void k6_reduce(
    const float* __restrict__ part,
    const float* __restrict__ bias,
    bf16* __restrict__ h1)
{
    int i = blockIdx.x * 256 + threadIdx.x;
    const f32x4* p = (const f32x4*)part;
    f32x4 s0 = p[i], s1v = p[i + 409600], s2v = p[i + 819200], s3v = p[i + 1228800];
    int nn = (i * 4) % 400;
    f32x4 bv = *(const f32x4*)&bias[nn];
    bf16x4 ov;
    ov[0] = (bf16)fmaxf(s0[0] + s1v[0] + s2v[0] + s3v[0] + bv[0], 0.f);
    ov[1] = (bf16)fmaxf(s0[1] + s1v[1] + s2v[1] + s3v[1] + bv[1], 0.f);
    ov[2] = (bf16)fmaxf(s0[2] + s1v[2] + s2v[2] + s3v[2] + bv[2], 0.f);
    ov[3] = (bf16)fmaxf(s0[3] + s1v[3] + s2v[3] + s3v[3] + bv[3], 0.f);
    *(bf16x4*)&h1[i * 4] = ov;
}

// ---------------- K7: MLP2  h2 = relu(h1 @ Wl2^T + bl2) ----------------
__global__ __launch_bounds__(256) void k7_mlp2(
    const bf16* __restrict__ A,           // [4096][400] bf16
    const float* __restrict__ Bw,         // [64][400] f32
    const float* __restrict__ bias,
    float* __restrict__ Cout)             // [4096][64]
{
    __shared__ bf16 As[16 * 416];
    int tid = threadIdx.x;
    int m0 = blockIdx.x * 16;
    for (int i = tid; i < 16 * 50; i += 256) {
        int rr = i / 50, cc = (i % 50) * 8;
        *(bf16x8*)&As[rr * 416 + cc] = *(const bf16x8*)(A + (size_t)(m0 + rr) * 400 + cc);
    }
    if (tid < 32) {
        int rr = tid >> 1, cc = 400 + (tid & 1) * 8;
        bf16x8 z;
#pragma unroll
        for (int k = 0; k < 8; ++k) z[k] = (bf16)0.f;
        *(bf16x8*)&As[rr * 416 + cc] = z;
    }
    __syncthreads();

    int w = tid >> 6, lane = tid & 63, q = lane >> 4, r15 = lane & 15;
    f32x4 acc = {0.f, 0.f, 0.f, 0.f};
    const float* pB = Bw + (size_t)(w * 16 + r15) * 400;
#pragma unroll 4
    for (int kt = 0; kt < 13; ++kt) {
        int k0 = kt * 32 + q * 8;
        bf16x8 a = *(const bf16x8*)&As[r15 * 416 + k0];
        bf16x8 bb;
#pragma unroll
        for (int k = 0; k < 8; ++k) bb[k] = (bf16)0.f;
        if (k0 < 400) {
            f32x4 c0 = *(const f32x4*)(pB + k0);
            f32x4 c1 = *(const f32x4*)(pB + k0 + 4);
            bb[0] = (bf16)c0[0]; bb[1] = (bf16)c0[1]; bb[2] = (bf16)c0[2]; bb[3] = (bf16)c0[3];
            bb[4] = (bf16)c1[0]; bb[5] = (bf16)c1[1]; bb[6] = (bf16)c1[2]; bb[7] = (bf16)c1[3];
        }
        acc = __builtin_amdgcn_mfma_f32_16x16x32_bf16(a, bb, acc, 0, 0, 0);
    }
#pragma unroll
    for (int r = 0; r < 4; ++r) {
        int mm = m0 + q * 4 + r;
        int nn = w * 16 + r15;
        float v = fmaxf(acc[r] + bias[nn], 0.f);
        Cout[(size_t)mm * 64 + nn] = v;
    }
}

// ---------------- K8: BN2+relu+maxpool + concat + FC ----------------
__global__ __launch_bounds__(256) void k8_final(
    const bf16* __restrict__ g2out,
    const float* __restrict__ scale2, const float* __restrict__ shift2,
    const float* __restrict__ h2,
    const float* __restrict__ Wfc,
    const float* __restrict__ bfc,
    float* __restrict__ out)
{
    __shared__ float s2s[64], sh2s[64];
    int tid = threadIdx.x;
    if (tid < 64) { s2s[tid] = scale2[tid]; sh2s[tid] = shift2[tid]; }
    __syncthreads();
    int w = tid >> 6, lane = tid & 63;
    int b = blockIdx.x * 4 + w;
    int c = lane & 31, half = lane >> 5;
    const bf16* gb = g2out + (size_t)b * 2048;
    float mx = 0.f;
    for (int i = 0; i < 32; ++i) {
        int n = half * 32 + i;
        float v = (float)gb[n * 32 + c];
        float val = fmaf(s2s[n], v, sh2s[n]);
        mx = fmaxf(mx, val);
    }
    mx = fmaxf(mx, __shfl_xor(mx, 32));
    float h2v = h2[(size_t)b * 64 + lane];
#pragma unroll
    for (int o = 0; o < 2; ++o) {
        float t = h2v * Wfc[o * 96 + 32 + lane];
        if (half == 0) t += mx * Wfc[o * 96 + c];
#pragma unroll
        for (int off = 32; off > 0; off >>= 1) t += __shfl_xor(t, off);
        if (lane == 0) out[(size_t)b * 2 + o] = t + bfc[o];
    }
}

extern "C" void kernel_launch(void* const* d_in, const int* in_sizes, int n_in,
                              void* d_out, int out_size, void* d_ws, size_t ws_size,
                              hipStream_t stream)
{
    const float* x_fp   = (const float*)d_in[0];
    const float* x_node = (const float*)d_in[1];
    const int*   edge   = (const int*)d_in[2];
    const float* W1     = (const float*)d_in[3];
    const float* b1     = (const float*)d_in[4];
    const float* g1     = (const float*)d_in[5];
    const float* be1    = (const float*)d_in[6];
    const float* W2     = (const float*)d_in[7];
    const float* b2     = (const float*)d_in[8];
    const float* g2     = (const float*)d_in[9];
    const float* be2    = (const float*)d_in[10];
    const float* Wl1    = (const float*)d_in[11];
    const float* bl1    = (const float*)d_in[12];
    const float* Wl2    = (const float*)d_in[13];
    const float* bl2    = (const float*)d_in[14];
    const float* Wfc    = (const float*)d_in[15];
    const float* bfc    = (const float*)d_in[16];
    float* out = (float*)d_out;

    char* ws = (char*)d_ws;
    bf16*  w1b     = (bf16*)(ws);                     // 13312
    bf16*  ahb     = (bf16*)(ws + 13312);             // 9216
    bf16*  w2b     = (bf16*)(ws + 22528);             // 4608
    float* scale1  = (float*)(ws + 27136);
    float* shift1  = (float*)(ws + 27392);
    float* scale2  = (float*)(ws + 27648);
    float* shift2  = (float*)(ws + 27904);
    float* part1   = (float*)(ws + 28672);            // 65536
    float* part2   = (float*)(ws + 94208);            // 65536
    char*  pool    = ws + 196608;
    bf16*  g1out   = (bf16*)(pool);                   // 33,554,432
    bf16*  g2out   = (bf16*)(pool + 33554432ull);     // 16,777,216
    float* part6   = (float*)(pool + 50331648ull);    // 26,214,400
    bf16*  h1      = (bf16*)(pool + 76546048ull);     //  3,276,800
    float* h2      = (float*)(pool + 79822848ull);    //  1,048,576

    k0_prep<<<dim3(16), dim3(256), 0, stream>>>(edge, W1, W2, part1, ahb, w1b, w2b);
    k1_gcn1<<<dim3(4096), dim3(256), 0, stream>>>(x_node, w1b, ahb, b1, g1out, part1);
    k_bnstats<<<dim3(64), dim3(64), 0, stream>>>(part1, g1, be1, scale1, shift1,
                                                 1.f / (4096.f * 64.f));
    k3_gcn2<<<dim3(4096), dim3(256), 0, stream>>>(g1out, w2b, ahb, b2, scale1, shift1,
                                                  g2out, part2);
    k_bnstats<<<dim3(64), dim3(64), 0, stream>>>(part2, g2, be2, scale2, shift2,
                                                 1.f / (4096.f * 32.f));
    k6_mlp1<<<dim3(64, 7, 4), dim3(256), 0, stream>>>(x_fp, Wl1, part6);
    k6_reduce<<<dim3(1600), dim3(256), 0, stream>>>(part6, bl1, h1);
    k7_mlp2<<<dim3(256), dim3(256), 0, stream>>>(h1, Wl2, bl2, h2);
    k8_final<<<dim3(1024), dim3(256), 0, stream>>>(g2out, scale2, shift2, h2, Wfc, bfc, out);
}